// Round 5
// baseline (176.037 us; speedup 1.0000x reference)
//
#include <hip/hip_runtime.h>

#define THREADS 256

typedef __attribute__((ext_vector_type(8))) short bf16x8;
typedef __attribute__((ext_vector_type(16))) float f32x16;

__device__ __forceinline__ bool lex_lt(float av, int ai, float bv, int bi) {
  return av < bv || (av == bv && ai < bi);
}

// round-to-nearest-even fp32 -> bf16 (returned as low 16 bits)
__device__ __forceinline__ unsigned bf16_rne(float v) {
  unsigned u = __float_as_uint(v);
  return (u + 0x7fffu + ((u >> 16) & 1u)) >> 16;
}

// ---------------------------------------------------------------------------
// vq_pre (merged): blocks 0..63 build the k-major bf16-split codebook planes
// wh[kg][n][8], wl[kg][n][8]; blocks 64..65 compute e2[k] in fp64.
// ---------------------------------------------------------------------------
__global__ __launch_bounds__(THREADS) void vq_pre(
    const float* __restrict__ w, float* __restrict__ e2,
    short* __restrict__ wtil) {
  int blk = blockIdx.x;
  if (blk < 64) {
    int gid = blk * THREADS + threadIdx.x;  // 16384 threads
    int n  = gid & 511;
    int kg = gid >> 9;
    bf16x8 hv, lv;
#pragma unroll
    for (int j = 0; j < 8; ++j) {
      float v = w[(kg * 8 + j) * 512 + n];
      unsigned h = bf16_rne(v);
      float hf = __uint_as_float(h << 16);
      unsigned l = bf16_rne(v - hf);
      hv[j] = (short)h;
      lv[j] = (short)l;
    }
    short* dst = wtil + (size_t)gid * 8;   // (kg*512 + n)*8
    *(bf16x8*)dst = hv;
    *(bf16x8*)(dst + 131072) = lv;
  } else {
    int k = (blk - 64) * THREADS + threadIdx.x;  // 0..511
    double s = 0.0;
#pragma unroll 8
    for (int d = 0; d < 256; ++d) {
      double v = (double)w[d * 512 + k];
      s = fma(v, v, s);
    }
    e2[k] = (float)s;
  }
}

// ---------------------------------------------------------------------------
// vq_main: block = 64 positions x 512 codes. bf16 3-split MFMA GEMM with
// 1-chunk-ahead B prefetch; vectorized LDS staging; top-2 + fp64 tie
// refinement; fused gather-write of the output slab.
// ---------------------------------------------------------------------------
__global__ __launch_bounds__(THREADS, 2) void vq_main(
    const float* __restrict__ x, const float* __restrict__ w,
    const float* __restrict__ e2g, const short* __restrict__ wtil,
    float* __restrict__ out, float* __restrict__ arg_out) {
  __shared__ short xh[16384];   // [m][k] swizzled: off = m*256 + ((kg^(m&7))<<3) + (k&7)
  __shared__ short xl[16384];
  __shared__ float tv1[256], tv2[256];
  __shared__ int   ti1[256], ti2[256];
  __shared__ int   pickS[64];

  const int tid = threadIdx.x;
  const int b  = blockIdx.x >> 4;
  const int n0 = (blockIdx.x & 15) << 6;
  const float* xbase = x + (size_t)b * 262144 + n0;

  // ---- staging: per thread 2 reps x (8 coalesced float4 loads -> 8 b128 LDS writes)
  {
    const int n4  = tid & 15;       // m base / 4
    const int kgp = tid >> 4;       // 0..15
#pragma unroll
    for (int rep = 0; rep < 2; ++rep) {
      int kg = kgp + (rep << 4);
      float4 v[8];
#pragma unroll
      for (int j = 0; j < 8; ++j)
        v[j] = *(const float4*)(xbase + (size_t)(kg * 8 + j) * 1024 + (n4 << 2));
#pragma unroll
      for (int i = 0; i < 4; ++i) {
        int m = (n4 << 2) + i;
        bf16x8 hv, lv;
#pragma unroll
        for (int j = 0; j < 8; ++j) {
          float f = (i == 0) ? v[j].x : (i == 1) ? v[j].y : (i == 2) ? v[j].z : v[j].w;
          unsigned h = bf16_rne(f);
          unsigned l = bf16_rne(f - __uint_as_float(h << 16));
          hv[j] = (short)h;
          lv[j] = (short)l;
        }
        int off = (m << 8) + ((kg ^ (m & 7)) << 3);
        *(bf16x8*)&xh[off] = hv;
        *(bf16x8*)&xl[off] = lv;
      }
    }
  }
  __syncthreads();

  const int lane = tid & 63;
  const int wv   = tid >> 6;     // wave = n-quarter
  const int ln   = lane & 31;
  const int half = lane >> 5;
  const int wb   = wv << 7;      // wave n base (128 codes per wave)

  f32x16 acc[2][4];
#pragma unroll
  for (int mt = 0; mt < 2; ++mt)
#pragma unroll
    for (int nt = 0; nt < 4; ++nt)
#pragma unroll
      for (int r = 0; r < 16; ++r) acc[mt][nt][r] = 0.f;

  const int m0 = ln, m1 = 32 + ln;
  const int a0base = m0 << 8, a1base = m1 << 8;
  const int a0sw = m0 & 7, a1sw = m1 & 7;

  size_t bofs[4];
#pragma unroll
  for (int nt = 0; nt < 4; ++nt) bofs[nt] = (size_t)((wb + (nt << 5) + ln) << 3);

  // prefetch chunk 0 B fragments
  bf16x8 pbh[4], pbl[4];
#pragma unroll
  for (int nt = 0; nt < 4; ++nt) {
    const short* p = wtil + ((size_t)half << 12) + bofs[nt];
    pbh[nt] = *(const bf16x8*)p;
    pbl[nt] = *(const bf16x8*)(p + 131072);
  }

#pragma unroll
  for (int ch = 0; ch < 16; ++ch) {
    const int kg = (ch << 1) + half;
    // A fragments for this chunk (LDS, conflict-spread via XOR swizzle)
    bf16x8 ah0 = *(const bf16x8*)&xh[a0base + ((kg ^ a0sw) << 3)];
    bf16x8 al0 = *(const bf16x8*)&xl[a0base + ((kg ^ a0sw) << 3)];
    bf16x8 ah1 = *(const bf16x8*)&xh[a1base + ((kg ^ a1sw) << 3)];
    bf16x8 al1 = *(const bf16x8*)&xl[a1base + ((kg ^ a1sw) << 3)];
    // consume prefetched B, then issue next chunk's loads
    bf16x8 bh[4], bl[4];
#pragma unroll
    for (int nt = 0; nt < 4; ++nt) { bh[nt] = pbh[nt]; bl[nt] = pbl[nt]; }
    if (ch < 15) {
      const int kgn = ((ch + 1) << 1) + half;
#pragma unroll
      for (int nt = 0; nt < 4; ++nt) {
        const short* p = wtil + ((size_t)kgn << 12) + bofs[nt];
        pbh[nt] = *(const bf16x8*)p;
        pbl[nt] = *(const bf16x8*)(p + 131072);
      }
    }
#pragma unroll
    for (int nt = 0; nt < 4; ++nt) {
      acc[0][nt] = __builtin_amdgcn_mfma_f32_32x32x16_bf16(ah0, bh[nt], acc[0][nt], 0, 0, 0);
      acc[0][nt] = __builtin_amdgcn_mfma_f32_32x32x16_bf16(ah0, bl[nt], acc[0][nt], 0, 0, 0);
      acc[0][nt] = __builtin_amdgcn_mfma_f32_32x32x16_bf16(al0, bh[nt], acc[0][nt], 0, 0, 0);
      acc[1][nt] = __builtin_amdgcn_mfma_f32_32x32x16_bf16(ah1, bh[nt], acc[1][nt], 0, 0, 0);
      acc[1][nt] = __builtin_amdgcn_mfma_f32_32x32x16_bf16(ah1, bl[nt], acc[1][nt], 0, 0, 0);
      acc[1][nt] = __builtin_amdgcn_mfma_f32_32x32x16_bf16(al1, bh[nt], acc[1][nt], 0, 0, 0);
    }
  }

  // ---- epilogue: per-row top-2 (verified absmax-0 logic, unchanged)
  float e2v[4];
#pragma unroll
  for (int nt = 0; nt < 4; ++nt) e2v[nt] = e2g[wb + (nt << 5) + ln];

#pragma unroll
  for (int mt = 0; mt < 2; ++mt) {
#pragma unroll
    for (int r = 0; r < 16; ++r) {
      int row = (mt << 5) + (r & 3) + ((r >> 2) << 3) + (half << 2);
      float v1 = 3.4e38f, v2 = 3.4e38f;
      int i1 = 0x7fffffff, i2 = 0x7fffffff;
#pragma unroll
      for (int nt = 0; nt < 4; ++nt) {
        int k = wb + (nt << 5) + ln;
        float s = fmaf(-2.f, acc[mt][nt][r], e2v[nt]);
        if (lex_lt(s, k, v1, i1)) { v2 = v1; i2 = i1; v1 = s; i1 = k; }
        else if (lex_lt(s, k, v2, i2)) { v2 = s; i2 = k; }
      }
#pragma unroll
      for (int off = 16; off >= 1; off >>= 1) {
        float ov1 = __shfl_xor(v1, off);
        int   oi1 = __shfl_xor(i1, off);
        float ov2 = __shfl_xor(v2, off);
        int   oi2 = __shfl_xor(i2, off);
        bool aFirst = lex_lt(v1, i1, ov1, oi1);
        float nv1 = aFirst ? v1 : ov1;  int ni1 = aFirst ? i1 : oi1;
        float cv  = aFirst ? ov1 : v1;  int ci  = aFirst ? oi1 : i1;
        float sv  = aFirst ? v2 : ov2;  int si  = aFirst ? i2 : oi2;
        bool cFirst = lex_lt(cv, ci, sv, si);
        v1 = nv1; i1 = ni1;
        v2 = cFirst ? cv : sv; i2 = cFirst ? ci : si;
      }
      if (ln == 0) {
        int s = wv * 64 + row;
        tv1[s] = v1; ti1[s] = i1; tv2[s] = v2; ti2[s] = i2;
      }
    }
  }
  __syncthreads();

  // ---- final cross-wave merge + fp64 refinement (exact x, w from global)
  if (tid < 64) {
    int row = tid;
    float v1 = 3.4e38f, v2 = 3.4e38f;
    int i1 = 0x7fffffff, i2 = 0x7fffffff;
#pragma unroll
    for (int wvv = 0; wvv < 4; ++wvv) {
      int s = wvv * 64 + row;
      float a1 = tv1[s]; int ai = ti1[s];
      float a2 = tv2[s]; int bi = ti2[s];
      if (lex_lt(a1, ai, v1, i1)) { v2 = v1; i2 = i1; v1 = a1; i1 = ai; }
      else if (lex_lt(a1, ai, v2, i2)) { v2 = a1; i2 = ai; }
      if (lex_lt(a2, bi, v1, i1)) { v2 = v1; i2 = i1; v1 = a2; i1 = bi; }
      else if (lex_lt(a2, bi, v2, i2)) { v2 = a2; i2 = bi; }
    }
    int pick = i1;
    if (v2 - v1 < 0.05f) {
      double s1 = 0.0, s2 = 0.0;
      const float* xp = x + (size_t)b * 262144 + n0 + row;
#pragma unroll 4
      for (int k = 0; k < 256; ++k) {
        double xv = (double)xp[(size_t)k * 1024];
        double w1 = (double)w[k * 512 + i1];
        double w2 = (double)w[k * 512 + i2];
        double t1 = xv - w1, t2 = xv - w2;
        s1 = fma(t1, t1, s1);
        s2 = fma(t2, t2, s2);
      }
      if (s2 < s1 || (s2 == s1 && i2 < i1)) pick = i2;
    }
    int p = b * 1024 + n0 + row;
    arg_out[p] = (float)pick;
    pickS[row] = pick;
  }
  __syncthreads();

  // ---- fused gather: out[b][d][n0+nn] = w[d][pick[nn]]
  {
    const int nn0 = (tid & 15) << 2;
    const int d0g = tid >> 4;          // 0..15
    int pk0 = pickS[nn0], pk1 = pickS[nn0 + 1], pk2 = pickS[nn0 + 2], pk3 = pickS[nn0 + 3];
    float* obase = out + (size_t)b * 262144 + n0 + nn0;
#pragma unroll
    for (int dg = 0; dg < 16; ++dg) {
      int d = d0g + (dg << 4);
      const float* wr = w + d * 512;
      float4 o = make_float4(wr[pk0], wr[pk1], wr[pk2], wr[pk3]);
      *(float4*)(obase + (size_t)d * 1024) = o;
    }
  }
}

// ---------------------------------------------------------------------------
extern "C" void kernel_launch(void* const* d_in, const int* in_sizes, int n_in,
                              void* d_out, int out_size, void* d_ws, size_t ws_size,
                              hipStream_t stream) {
  const float* x = (const float*)d_in[0];
  const float* w = (const float*)d_in[1];
  float* out  = (float*)d_out;
  float* argf = out + 8388608;
  float* e2   = (float*)d_ws;                 // 512 floats
  short* wtil = (short*)(e2 + 512);           // 2 planes x 131072 shorts = 512 KB

  vq_pre<<<66, THREADS, 0, stream>>>(w, e2, wtil);
  vq_main<<<512, THREADS, 0, stream>>>(x, w, e2, wtil, out, argf);
}

// Round 6
// 169.034 us; speedup vs baseline: 1.0414x; 1.0414x over previous
//
#include <hip/hip_runtime.h>

typedef __attribute__((ext_vector_type(8))) short bf16x8;
typedef __attribute__((ext_vector_type(16))) float f32x16;

__device__ __forceinline__ bool lex_lt(float av, int ai, float bv, int bi) {
  return av < bv || (av == bv && ai < bi);
}

// round-to-nearest-even fp32 -> bf16 (returned as low 16 bits)
__device__ __forceinline__ unsigned bf16_rne(float v) {
  unsigned u = __float_as_uint(v);
  return (u + 0x7fffu + ((u >> 16) & 1u)) >> 16;
}

// ---------------------------------------------------------------------------
// vq_pre: blocks 0..63 build k-major bf16-split codebook planes
// wh[kg][n][8], wl[kg][n][8]; blocks 64..71 compute e2[k] in fp64 with a
// 4-way d-split per k (parallelism: 2048 threads vs 512 before).
// ---------------------------------------------------------------------------
__global__ __launch_bounds__(256) void vq_pre(
    const float* __restrict__ w, float* __restrict__ e2,
    short* __restrict__ wtil) {
  int blk = blockIdx.x;
  if (blk < 64) {
    int gid = blk * 256 + threadIdx.x;  // 16384 threads
    int n  = gid & 511;
    int kg = gid >> 9;
    bf16x8 hv, lv;
#pragma unroll
    for (int j = 0; j < 8; ++j) {
      float v = w[(kg * 8 + j) * 512 + n];
      unsigned h = bf16_rne(v);
      float hf = __uint_as_float(h << 16);
      unsigned l = bf16_rne(v - hf);
      hv[j] = (short)h;
      lv[j] = (short)l;
    }
    short* dst = wtil + (size_t)gid * 8;   // (kg*512 + n)*8
    *(bf16x8*)dst = hv;
    *(bf16x8*)(dst + 131072) = lv;
  } else {
    int t = (blk - 64) * 256 + threadIdx.x;  // 0..2047
    int k = t >> 2;
    int part = t & 3;
    double s = 0.0;
#pragma unroll 8
    for (int d = part * 64; d < part * 64 + 64; ++d) {
      double v = (double)w[d * 512 + k];
      s = fma(v, v, s);
    }
    s += __shfl_xor(s, 1);
    s += __shfl_xor(s, 2);
    if (part == 0) e2[k] = (float)s;
  }
}

// ---------------------------------------------------------------------------
// vq_main: 512 threads (8 waves). Block = 64 positions x 512 codes; wave wv
// owns codes [wv*64, wv*64+64) over all 64 rows -> acc 2x2 (64 AGPR).
// bf16 3-split MFMA GEMM, B prefetched 1 chunk ahead, barrier-free K-loop.
// launch_bounds(512,4): 128 regs/wave -> 4 waves/SIMD, 16 waves/CU.
// ---------------------------------------------------------------------------
__global__ __launch_bounds__(512, 4) void vq_main(
    const float* __restrict__ x, const float* __restrict__ w,
    const float* __restrict__ e2g, const short* __restrict__ wtil,
    float* __restrict__ out, float* __restrict__ arg_out) {
  __shared__ short xh[16384];   // [m][k] swizzled: off = m*256 + ((kg^(m&7))<<3) + (k&7)
  __shared__ short xl[16384];
  __shared__ float tv1[512], tv2[512];
  __shared__ int   ti1[512], ti2[512];
  __shared__ int   pickS[64];

  const int tid = threadIdx.x;
  const int b  = blockIdx.x >> 4;
  const int n0 = (blockIdx.x & 15) << 6;
  const float* xbase = x + (size_t)b * 262144 + n0;

  // ---- staging: 512 threads, each: 8 coalesced float4 loads -> 8 b128 writes
  {
    const int n4  = tid & 15;       // m base / 4
    const int kg  = tid >> 4;       // 0..31
    float4 v[8];
#pragma unroll
    for (int j = 0; j < 8; ++j)
      v[j] = *(const float4*)(xbase + (size_t)(kg * 8 + j) * 1024 + (n4 << 2));
#pragma unroll
    for (int i = 0; i < 4; ++i) {
      int m = (n4 << 2) + i;
      bf16x8 hv, lv;
#pragma unroll
      for (int j = 0; j < 8; ++j) {
        float f = (i == 0) ? v[j].x : (i == 1) ? v[j].y : (i == 2) ? v[j].z : v[j].w;
        unsigned h = bf16_rne(f);
        unsigned l = bf16_rne(f - __uint_as_float(h << 16));
        hv[j] = (short)h;
        lv[j] = (short)l;
      }
      int off = (m << 8) + ((kg ^ (m & 7)) << 3);
      *(bf16x8*)&xh[off] = hv;
      *(bf16x8*)&xl[off] = lv;
    }
  }
  __syncthreads();

  const int lane = tid & 63;
  const int wv   = tid >> 6;     // wave 0..7: codes [wv*64, wv*64+64)
  const int ln   = lane & 31;
  const int half = lane >> 5;
  const int wb   = wv << 6;

  f32x16 acc[2][2];
#pragma unroll
  for (int mt = 0; mt < 2; ++mt)
#pragma unroll
    for (int nt = 0; nt < 2; ++nt)
#pragma unroll
      for (int r = 0; r < 16; ++r) acc[mt][nt][r] = 0.f;

  const int m0 = ln, m1 = 32 + ln;
  const int a0base = m0 << 8, a1base = m1 << 8;
  const int a0sw = m0 & 7, a1sw = m1 & 7;

  size_t bofs[2];
#pragma unroll
  for (int nt = 0; nt < 2; ++nt) bofs[nt] = (size_t)((wb + (nt << 5) + ln) << 3);

  // prefetch chunk 0 B fragments
  bf16x8 pbh[2], pbl[2];
#pragma unroll
  for (int nt = 0; nt < 2; ++nt) {
    const short* p = wtil + ((size_t)half << 12) + bofs[nt];
    pbh[nt] = *(const bf16x8*)p;
    pbl[nt] = *(const bf16x8*)(p + 131072);
  }

#pragma unroll
  for (int ch = 0; ch < 16; ++ch) {
    const int kg = (ch << 1) + half;
    bf16x8 ah0 = *(const bf16x8*)&xh[a0base + ((kg ^ a0sw) << 3)];
    bf16x8 al0 = *(const bf16x8*)&xl[a0base + ((kg ^ a0sw) << 3)];
    bf16x8 ah1 = *(const bf16x8*)&xh[a1base + ((kg ^ a1sw) << 3)];
    bf16x8 al1 = *(const bf16x8*)&xl[a1base + ((kg ^ a1sw) << 3)];
    bf16x8 bh[2], bl[2];
#pragma unroll
    for (int nt = 0; nt < 2; ++nt) { bh[nt] = pbh[nt]; bl[nt] = pbl[nt]; }
    if (ch < 15) {
      const int kgn = ((ch + 1) << 1) + half;
#pragma unroll
      for (int nt = 0; nt < 2; ++nt) {
        const short* p = wtil + ((size_t)kgn << 12) + bofs[nt];
        pbh[nt] = *(const bf16x8*)p;
        pbl[nt] = *(const bf16x8*)(p + 131072);
      }
    }
#pragma unroll
    for (int nt = 0; nt < 2; ++nt) {
      acc[0][nt] = __builtin_amdgcn_mfma_f32_32x32x16_bf16(ah0, bh[nt], acc[0][nt], 0, 0, 0);
      acc[0][nt] = __builtin_amdgcn_mfma_f32_32x32x16_bf16(ah0, bl[nt], acc[0][nt], 0, 0, 0);
      acc[0][nt] = __builtin_amdgcn_mfma_f32_32x32x16_bf16(al0, bh[nt], acc[0][nt], 0, 0, 0);
      acc[1][nt] = __builtin_amdgcn_mfma_f32_32x32x16_bf16(ah1, bh[nt], acc[1][nt], 0, 0, 0);
      acc[1][nt] = __builtin_amdgcn_mfma_f32_32x32x16_bf16(ah1, bl[nt], acc[1][nt], 0, 0, 0);
      acc[1][nt] = __builtin_amdgcn_mfma_f32_32x32x16_bf16(al1, bh[nt], acc[1][nt], 0, 0, 0);
    }
  }

  // ---- epilogue: per-row top-2 (verified logic), per wave over its 64 codes
  float e2v[2];
#pragma unroll
  for (int nt = 0; nt < 2; ++nt) e2v[nt] = e2g[wb + (nt << 5) + ln];

#pragma unroll
  for (int mt = 0; mt < 2; ++mt) {
#pragma unroll
    for (int r = 0; r < 16; ++r) {
      int row = (mt << 5) + (r & 3) + ((r >> 2) << 3) + (half << 2);
      float v1 = 3.4e38f, v2 = 3.4e38f;
      int i1 = 0x7fffffff, i2 = 0x7fffffff;
#pragma unroll
      for (int nt = 0; nt < 2; ++nt) {
        int k = wb + (nt << 5) + ln;
        float s = fmaf(-2.f, acc[mt][nt][r], e2v[nt]);
        if (lex_lt(s, k, v1, i1)) { v2 = v1; i2 = i1; v1 = s; i1 = k; }
        else if (lex_lt(s, k, v2, i2)) { v2 = s; i2 = k; }
      }
#pragma unroll
      for (int off = 16; off >= 1; off >>= 1) {
        float ov1 = __shfl_xor(v1, off);
        int   oi1 = __shfl_xor(i1, off);
        float ov2 = __shfl_xor(v2, off);
        int   oi2 = __shfl_xor(i2, off);
        bool aFirst = lex_lt(v1, i1, ov1, oi1);
        float nv1 = aFirst ? v1 : ov1;  int ni1 = aFirst ? i1 : oi1;
        float cv  = aFirst ? ov1 : v1;  int ci  = aFirst ? oi1 : i1;
        float sv  = aFirst ? v2 : ov2;  int si  = aFirst ? i2 : oi2;
        bool cFirst = lex_lt(cv, ci, sv, si);
        v1 = nv1; i1 = ni1;
        v2 = cFirst ? cv : sv; i2 = cFirst ? ci : si;
      }
      if (ln == 0) {
        int s = (wv << 6) + row;
        tv1[s] = v1; ti1[s] = i1; tv2[s] = v2; ti2[s] = i2;
      }
    }
  }
  __syncthreads();

  // ---- final cross-wave merge + fp64 refinement (exact x, w from global)
  if (tid < 64) {
    int row = tid;
    float v1 = 3.4e38f, v2 = 3.4e38f;
    int i1 = 0x7fffffff, i2 = 0x7fffffff;
#pragma unroll
    for (int wvv = 0; wvv < 8; ++wvv) {
      int s = (wvv << 6) + row;
      float a1 = tv1[s]; int ai = ti1[s];
      float a2 = tv2[s]; int bi = ti2[s];
      if (lex_lt(a1, ai, v1, i1)) { v2 = v1; i2 = i1; v1 = a1; i1 = ai; }
      else if (lex_lt(a1, ai, v2, i2)) { v2 = a1; i2 = ai; }
      if (lex_lt(a2, bi, v1, i1)) { v2 = v1; i2 = i1; v1 = a2; i1 = bi; }
      else if (lex_lt(a2, bi, v2, i2)) { v2 = a2; i2 = bi; }
    }
    int pick = i1;
    if (v2 - v1 < 0.05f) {
      double s1 = 0.0, s2 = 0.0;
      const float* xp = x + (size_t)b * 262144 + n0 + row;
#pragma unroll 4
      for (int k = 0; k < 256; ++k) {
        double xv = (double)xp[(size_t)k * 1024];
        double w1 = (double)w[k * 512 + i1];
        double w2 = (double)w[k * 512 + i2];
        double t1 = xv - w1, t2 = xv - w2;
        s1 = fma(t1, t1, s1);
        s2 = fma(t2, t2, s2);
      }
      if (s2 < s1 || (s2 == s1 && i2 < i1)) pick = i2;
    }
    int p = b * 1024 + n0 + row;
    arg_out[p] = (float)pick;
    pickS[row] = pick;
  }
  __syncthreads();

  // ---- fused gather: out[b][d][n0+nn] = w[d][pick[nn]]
  {
    const int nn0 = (tid & 15) << 2;
    const int d0g = tid >> 4;          // 0..31
    int pk0 = pickS[nn0], pk1 = pickS[nn0 + 1], pk2 = pickS[nn0 + 2], pk3 = pickS[nn0 + 3];
    float* obase = out + (size_t)b * 262144 + n0 + nn0;
#pragma unroll
    for (int dg = 0; dg < 8; ++dg) {
      int d = d0g + (dg << 5);
      const float* wr = w + d * 512;
      float4 o = make_float4(wr[pk0], wr[pk1], wr[pk2], wr[pk3]);
      *(float4*)(obase + (size_t)d * 1024) = o;
    }
  }
}

// ---------------------------------------------------------------------------
extern "C" void kernel_launch(void* const* d_in, const int* in_sizes, int n_in,
                              void* d_out, int out_size, void* d_ws, size_t ws_size,
                              hipStream_t stream) {
  const float* x = (const float*)d_in[0];
  const float* w = (const float*)d_in[1];
  float* out  = (float*)d_out;
  float* argf = out + 8388608;
  float* e2   = (float*)d_ws;                 // 512 floats
  short* wtil = (short*)(e2 + 512);           // 2 planes x 131072 shorts = 512 KB

  vq_pre<<<72, 256, 0, stream>>>(w, e2, wtil);
  vq_main<<<512, 512, 0, stream>>>(x, w, e2, wtil, out, argf);
}

// Round 7
// 142.796 us; speedup vs baseline: 1.2328x; 1.1837x over previous
//
#include <hip/hip_runtime.h>

typedef __attribute__((ext_vector_type(8))) short bf16x8;
typedef __attribute__((ext_vector_type(16))) float f32x16;

__device__ __forceinline__ bool lex_lt(float av, int ai, float bv, int bi) {
  return av < bv || (av == bv && ai < bi);
}

// round-to-nearest-even fp32 -> bf16 (returned as low 16 bits)
__device__ __forceinline__ unsigned bf16_rne(float v) {
  unsigned u = __float_as_uint(v);
  return (u + 0x7fffu + ((u >> 16) & 1u)) >> 16;
}

// ---------------------------------------------------------------------------
// vq_pre: blocks 0..63 build k-major bf16-split codebook planes
// wh[kg][n][8], wl[kg][n][8]; blocks 64..71 compute e2[k] in fp64 (4-way
// d-split per k).
// ---------------------------------------------------------------------------
__global__ __launch_bounds__(256) void vq_pre(
    const float* __restrict__ w, float* __restrict__ e2,
    short* __restrict__ wtil) {
  int blk = blockIdx.x;
  if (blk < 64) {
    int gid = blk * 256 + threadIdx.x;  // 16384 threads
    int n  = gid & 511;
    int kg = gid >> 9;
    bf16x8 hv, lv;
#pragma unroll
    for (int j = 0; j < 8; ++j) {
      float v = w[(kg * 8 + j) * 512 + n];
      unsigned h = bf16_rne(v);
      float hf = __uint_as_float(h << 16);
      unsigned l = bf16_rne(v - hf);
      hv[j] = (short)h;
      lv[j] = (short)l;
    }
    short* dst = wtil + (size_t)gid * 8;   // (kg*512 + n)*8
    *(bf16x8*)dst = hv;
    *(bf16x8*)(dst + 131072) = lv;
  } else {
    int t = (blk - 64) * 256 + threadIdx.x;  // 0..2047
    int k = t >> 2;
    int part = t & 3;
    double s = 0.0;
#pragma unroll 8
    for (int d = part * 64; d < part * 64 + 64; ++d) {
      double v = (double)w[d * 512 + k];
      s = fma(v, v, s);
    }
    s += __shfl_xor(s, 1);
    s += __shfl_xor(s, 2);
    if (part == 0) e2[k] = (float)s;
  }
}

// ---------------------------------------------------------------------------
// vq_main: 512 threads (8 waves). Block = 64 positions x 512 codes; wave wv
// owns codes [wv*64, wv*64+64). TRANSPOSED MFMA: A=codes, B=x positions ->
// D[code][pos], pos=lane&31, 16 codes/lane in regs -> argmin top-2 is a
// register-local scan + ONE shfl_xor(32) merge (no butterfly).
// ---------------------------------------------------------------------------
__global__ __launch_bounds__(512, 4) void vq_main(
    const float* __restrict__ x, const float* __restrict__ w,
    const float* __restrict__ e2g, const short* __restrict__ wtil,
    float* __restrict__ out, float* __restrict__ arg_out) {
  __shared__ short xh[16384];   // [m][k] swizzled: off = m*256 + ((kg^(m&7))<<3) + (k&7)
  __shared__ short xl[16384];
  __shared__ float e2s[512];
  __shared__ float tv1[512], tv2[512];
  __shared__ int   ti1[512], ti2[512];
  __shared__ int   pickS[64];

  const int tid = threadIdx.x;
  const int b  = blockIdx.x >> 4;
  const int n0 = (blockIdx.x & 15) << 6;
  const float* xbase = x + (size_t)b * 262144 + n0;

  // ---- staging: 512 threads, each: 8 coalesced float4 loads -> 8 b128 writes
  {
    const int n4  = tid & 15;       // m base / 4
    const int kg  = tid >> 4;       // 0..31
    float4 v[8];
#pragma unroll
    for (int j = 0; j < 8; ++j)
      v[j] = *(const float4*)(xbase + (size_t)(kg * 8 + j) * 1024 + (n4 << 2));
#pragma unroll
    for (int i = 0; i < 4; ++i) {
      int m = (n4 << 2) + i;
      bf16x8 hv, lv;
#pragma unroll
      for (int j = 0; j < 8; ++j) {
        float f = (i == 0) ? v[j].x : (i == 1) ? v[j].y : (i == 2) ? v[j].z : v[j].w;
        unsigned h = bf16_rne(f);
        unsigned l = bf16_rne(f - __uint_as_float(h << 16));
        hv[j] = (short)h;
        lv[j] = (short)l;
      }
      int off = (m << 8) + ((kg ^ (m & 7)) << 3);
      *(bf16x8*)&xh[off] = hv;
      *(bf16x8*)&xl[off] = lv;
    }
    if (tid < 512) e2s[tid] = e2g[tid];
  }
  __syncthreads();

  const int lane = tid & 63;
  const int wv   = tid >> 6;     // wave 0..7: codes [wv*64, wv*64+64)
  const int ln   = lane & 31;
  const int half = lane >> 5;
  const int wb   = wv << 6;

  f32x16 acc[2][2];   // [code-tile ct][pos-tile pt]
#pragma unroll
  for (int ct = 0; ct < 2; ++ct)
#pragma unroll
    for (int pt = 0; pt < 2; ++pt)
#pragma unroll
      for (int r = 0; r < 16; ++r) acc[ct][pt][r] = 0.f;

  const int m0 = ln, m1 = 32 + ln;
  const int a0base = m0 << 8, a1base = m1 << 8;
  const int a0sw = m0 & 7, a1sw = m1 & 7;

  size_t bofs[2];   // code-fragment offsets: code = wb + ct*32 + ln
#pragma unroll
  for (int ct = 0; ct < 2; ++ct) bofs[ct] = (size_t)((wb + (ct << 5) + ln) << 3);

  // prefetch chunk 0 code fragments
  bf16x8 pch[2], pcl[2];
#pragma unroll
  for (int ct = 0; ct < 2; ++ct) {
    const short* p = wtil + ((size_t)half << 12) + bofs[ct];
    pch[ct] = *(const bf16x8*)p;
    pcl[ct] = *(const bf16x8*)(p + 131072);
  }

#pragma unroll
  for (int ch = 0; ch < 16; ++ch) {
    const int kg = (ch << 1) + half;
    // x fragments (B operand): pt0 -> m=ln, pt1 -> m=32+ln
    bf16x8 xh0 = *(const bf16x8*)&xh[a0base + ((kg ^ a0sw) << 3)];
    bf16x8 xl0 = *(const bf16x8*)&xl[a0base + ((kg ^ a0sw) << 3)];
    bf16x8 xh1 = *(const bf16x8*)&xh[a1base + ((kg ^ a1sw) << 3)];
    bf16x8 xl1 = *(const bf16x8*)&xl[a1base + ((kg ^ a1sw) << 3)];
    bf16x8 cfh[2], cfl[2];
#pragma unroll
    for (int ct = 0; ct < 2; ++ct) { cfh[ct] = pch[ct]; cfl[ct] = pcl[ct]; }
    if (ch < 15) {
      const int kgn = ((ch + 1) << 1) + half;
#pragma unroll
      for (int ct = 0; ct < 2; ++ct) {
        const short* p = wtil + ((size_t)kgn << 12) + bofs[ct];
        pch[ct] = *(const bf16x8*)p;
        pcl[ct] = *(const bf16x8*)(p + 131072);
      }
    }
    // D[code][pos]: A=codes, B=x.  3-split: ch*xh + ch*xl + cl*xh
#pragma unroll
    for (int ct = 0; ct < 2; ++ct) {
      acc[ct][0] = __builtin_amdgcn_mfma_f32_32x32x16_bf16(cfh[ct], xh0, acc[ct][0], 0, 0, 0);
      acc[ct][0] = __builtin_amdgcn_mfma_f32_32x32x16_bf16(cfh[ct], xl0, acc[ct][0], 0, 0, 0);
      acc[ct][0] = __builtin_amdgcn_mfma_f32_32x32x16_bf16(cfl[ct], xh0, acc[ct][0], 0, 0, 0);
      acc[ct][1] = __builtin_amdgcn_mfma_f32_32x32x16_bf16(cfh[ct], xh1, acc[ct][1], 0, 0, 0);
      acc[ct][1] = __builtin_amdgcn_mfma_f32_32x32x16_bf16(cfh[ct], xl1, acc[ct][1], 0, 0, 0);
      acc[ct][1] = __builtin_amdgcn_mfma_f32_32x32x16_bf16(cfl[ct], xh1, acc[ct][1], 0, 0, 0);
    }
  }

  // ---- epilogue: per-lane register scan over 32 codes, one xor-32 merge
  float e2r[2][16];
#pragma unroll
  for (int ct = 0; ct < 2; ++ct)
#pragma unroll
    for (int r = 0; r < 16; ++r)
      e2r[ct][r] = e2s[wb + (ct << 5) + (r & 3) + ((r >> 2) << 3) + (half << 2)];

#pragma unroll
  for (int pt = 0; pt < 2; ++pt) {
    float v1 = 3.4e38f, v2 = 3.4e38f;
    int i1 = 0x7fffffff, i2 = 0x7fffffff;
#pragma unroll
    for (int ct = 0; ct < 2; ++ct) {
#pragma unroll
      for (int r = 0; r < 16; ++r) {
        int k = wb + (ct << 5) + (r & 3) + ((r >> 2) << 3) + (half << 2);
        float s = fmaf(-2.f, acc[ct][pt][r], e2r[ct][r]);
        if (lex_lt(s, k, v1, i1)) { v2 = v1; i2 = i1; v1 = s; i1 = k; }
        else if (lex_lt(s, k, v2, i2)) { v2 = s; i2 = k; }
      }
    }
    // merge the two half-lane partials (lanes ln and ln+32 share position)
    {
      float ov1 = __shfl_xor(v1, 32);
      int   oi1 = __shfl_xor(i1, 32);
      float ov2 = __shfl_xor(v2, 32);
      int   oi2 = __shfl_xor(i2, 32);
      bool aFirst = lex_lt(v1, i1, ov1, oi1);
      float nv1 = aFirst ? v1 : ov1;  int ni1 = aFirst ? i1 : oi1;
      float cv  = aFirst ? ov1 : v1;  int ci  = aFirst ? oi1 : i1;
      float sv  = aFirst ? v2 : ov2;  int si  = aFirst ? i2 : oi2;
      bool cFirst = lex_lt(cv, ci, sv, si);
      v1 = nv1; i1 = ni1;
      v2 = cFirst ? cv : sv; i2 = cFirst ? ci : si;
    }
    if (half == 0) {
      int s = (wv << 6) + (pt << 5) + ln;   // wave-slot for this position
      tv1[s] = v1; ti1[s] = i1; tv2[s] = v2; ti2[s] = i2;
    }
  }
  __syncthreads();

  // ---- final cross-wave merge + fp64 refinement (exact x, w from global)
  if (tid < 64) {
    int row = tid;
    float v1 = 3.4e38f, v2 = 3.4e38f;
    int i1 = 0x7fffffff, i2 = 0x7fffffff;
#pragma unroll
    for (int wvv = 0; wvv < 8; ++wvv) {
      int s = (wvv << 6) + row;
      float a1 = tv1[s]; int ai = ti1[s];
      float a2 = tv2[s]; int bi = ti2[s];
      if (lex_lt(a1, ai, v1, i1)) { v2 = v1; i2 = i1; v1 = a1; i1 = ai; }
      else if (lex_lt(a1, ai, v2, i2)) { v2 = a1; i2 = ai; }
      if (lex_lt(a2, bi, v1, i1)) { v2 = v1; i2 = i1; v1 = a2; i1 = bi; }
      else if (lex_lt(a2, bi, v2, i2)) { v2 = a2; i2 = bi; }
    }
    int pick = i1;
    if (v2 - v1 < 0.05f) {
      double s1 = 0.0, s2 = 0.0;
      const float* xp = x + (size_t)b * 262144 + n0 + row;
#pragma unroll 4
      for (int k = 0; k < 256; ++k) {
        double xv = (double)xp[(size_t)k * 1024];
        double w1 = (double)w[k * 512 + i1];
        double w2 = (double)w[k * 512 + i2];
        double t1 = xv - w1, t2 = xv - w2;
        s1 = fma(t1, t1, s1);
        s2 = fma(t2, t2, s2);
      }
      if (s2 < s1 || (s2 == s1 && i2 < i1)) pick = i2;
    }
    int p = b * 1024 + n0 + row;
    arg_out[p] = (float)pick;
    pickS[row] = pick;
  }
  __syncthreads();

  // ---- fused gather: out[b][d][n0+nn] = w[d][pick[nn]]
  {
    const int nn0 = (tid & 15) << 2;
    const int d0g = tid >> 4;          // 0..31
    int pk0 = pickS[nn0], pk1 = pickS[nn0 + 1], pk2 = pickS[nn0 + 2], pk3 = pickS[nn0 + 3];
    float* obase = out + (size_t)b * 262144 + n0 + nn0;
#pragma unroll
    for (int dg = 0; dg < 8; ++dg) {
      int d = d0g + (dg << 5);
      const float* wr = w + d * 512;
      float4 o = make_float4(wr[pk0], wr[pk1], wr[pk2], wr[pk3]);
      *(float4*)(obase + (size_t)d * 1024) = o;
    }
  }
}

// ---------------------------------------------------------------------------
extern "C" void kernel_launch(void* const* d_in, const int* in_sizes, int n_in,
                              void* d_out, int out_size, void* d_ws, size_t ws_size,
                              hipStream_t stream) {
  const float* x = (const float*)d_in[0];
  const float* w = (const float*)d_in[1];
  float* out  = (float*)d_out;
  float* argf = out + 8388608;
  float* e2   = (float*)d_ws;                 // 512 floats
  short* wtil = (short*)(e2 + 512);           // 2 planes x 131072 shorts = 512 KB

  vq_pre<<<72, 256, 0, stream>>>(w, e2, wtil);
  vq_main<<<512, 512, 0, stream>>>(x, w, e2, wtil, out, argf);
}

// Round 8
// 137.103 us; speedup vs baseline: 1.2840x; 1.0415x over previous
//
#include <hip/hip_runtime.h>

typedef __attribute__((ext_vector_type(8))) short bf16x8;
typedef __attribute__((ext_vector_type(16))) float f32x16;

__device__ __forceinline__ bool lex_lt(float av, int ai, float bv, int bi) {
  return av < bv || (av == bv && ai < bi);
}

// round-to-nearest-even fp32 -> bf16 (returned as low 16 bits)
__device__ __forceinline__ unsigned bf16_rne(float v) {
  unsigned u = __float_as_uint(v);
  return (u + 0x7fffu + ((u >> 16) & 1u)) >> 16;
}

// ---------------------------------------------------------------------------
// vq_pre: blocks 0..63 build k-major bf16-split codebook planes
// wh[kg][n][8], wl[kg][n][8] plus (if wT) an exact fp32 transposed codebook
// wT[n][d]; blocks 64..71 compute e2[k] in fp64 (4-way d-split per k).
// ---------------------------------------------------------------------------
__global__ __launch_bounds__(256) void vq_pre(
    const float* __restrict__ w, float* __restrict__ e2,
    short* __restrict__ wtil, float* __restrict__ wT) {
  int blk = blockIdx.x;
  if (blk < 64) {
    int gid = blk * 256 + threadIdx.x;  // 16384 threads
    int n  = gid & 511;
    int kg = gid >> 9;
    bf16x8 hv, lv;
    float vv[8];
#pragma unroll
    for (int j = 0; j < 8; ++j) {
      float v = w[(kg * 8 + j) * 512 + n];
      vv[j] = v;
      unsigned h = bf16_rne(v);
      float hf = __uint_as_float(h << 16);
      unsigned l = bf16_rne(v - hf);
      hv[j] = (short)h;
      lv[j] = (short)l;
    }
    short* dst = wtil + (size_t)gid * 8;   // (kg*512 + n)*8
    *(bf16x8*)dst = hv;
    *(bf16x8*)(dst + 131072) = lv;
    if (wT) {   // wT[n][kg*8 .. kg*8+7] = w[kg*8+j][n]
      float* p = wT + (size_t)n * 256 + kg * 8;
      *(float4*)p       = make_float4(vv[0], vv[1], vv[2], vv[3]);
      *(float4*)(p + 4) = make_float4(vv[4], vv[5], vv[6], vv[7]);
    }
  } else {
    int t = (blk - 64) * 256 + threadIdx.x;  // 0..2047
    int k = t >> 2;
    int part = t & 3;
    double s = 0.0;
#pragma unroll 8
    for (int d = part * 64; d < part * 64 + 64; ++d) {
      double v = (double)w[d * 512 + k];
      s = fma(v, v, s);
    }
    s += __shfl_xor(s, 1);
    s += __shfl_xor(s, 2);
    if (part == 0) e2[k] = (float)s;
  }
}

// ---------------------------------------------------------------------------
// vq_main: 512 threads (8 waves). Block = 64 positions x 512 codes.
// Transposed MFMA (A=codes, B=x) -> per-lane register argmin scan.
// Gather via LDS bounce buffer from wT (scatter-free) when wT != nullptr.
// ---------------------------------------------------------------------------
__global__ __launch_bounds__(512, 4) void vq_main(
    const float* __restrict__ x, const float* __restrict__ w,
    const float* __restrict__ e2g, const short* __restrict__ wtil,
    const float* __restrict__ wT,
    float* __restrict__ out, float* __restrict__ arg_out) {
  // arena layout (phase 1): xh[16384]s | xl[16384]s | e2s[512]f | tv1|tv2|ti1|ti2 [512] | pickS[64]
  // phase 2 (gather): gbuf = 64x265 floats at offset 0 (overlaps dead xh/xl/e2s/tv1-head)
  __shared__ __align__(16) char arena[76032];
  short* xh  = (short*)arena;                 // 32768 B
  short* xl  = (short*)(arena + 32768);       // 32768 B
  float* e2s = (float*)(arena + 65536);       // 2048 B
  float* tv1 = (float*)(arena + 67584);
  float* tv2 = (float*)(arena + 69632);
  int*   ti1 = (int*)(arena + 71680);
  int*   ti2 = (int*)(arena + 73728);
  int*   pickS = (int*)(arena + 75776);       // 256 B

  const int tid = threadIdx.x;
  const int b  = blockIdx.x >> 4;
  const int n0 = (blockIdx.x & 15) << 6;
  const float* xbase = x + (size_t)b * 262144 + n0;

  // ---- staging: 512 threads, each: 8 coalesced float4 loads -> 8 b128 writes
  {
    const int n4  = tid & 15;       // m base / 4
    const int kg  = tid >> 4;       // 0..31
    float4 v[8];
#pragma unroll
    for (int j = 0; j < 8; ++j)
      v[j] = *(const float4*)(xbase + (size_t)(kg * 8 + j) * 1024 + (n4 << 2));
#pragma unroll
    for (int i = 0; i < 4; ++i) {
      int m = (n4 << 2) + i;
      bf16x8 hv, lv;
#pragma unroll
      for (int j = 0; j < 8; ++j) {
        float f = (i == 0) ? v[j].x : (i == 1) ? v[j].y : (i == 2) ? v[j].z : v[j].w;
        unsigned h = bf16_rne(f);
        unsigned l = bf16_rne(f - __uint_as_float(h << 16));
        hv[j] = (short)h;
        lv[j] = (short)l;
      }
      int off = (m << 8) + ((kg ^ (m & 7)) << 3);
      *(bf16x8*)&xh[off] = hv;
      *(bf16x8*)&xl[off] = lv;
    }
    e2s[tid & 511] = e2g[tid & 511];
  }
  __syncthreads();

  const int lane = tid & 63;
  const int wv   = tid >> 6;     // wave 0..7: codes [wv*64, wv*64+64)
  const int ln   = lane & 31;
  const int half = lane >> 5;
  const int wb   = wv << 6;

  f32x16 acc[2][2];   // [code-tile ct][pos-tile pt]
#pragma unroll
  for (int ct = 0; ct < 2; ++ct)
#pragma unroll
    for (int pt = 0; pt < 2; ++pt)
#pragma unroll
      for (int r = 0; r < 16; ++r) acc[ct][pt][r] = 0.f;

  const int m0 = ln, m1 = 32 + ln;
  const int a0base = m0 << 8, a1base = m1 << 8;
  const int a0sw = m0 & 7, a1sw = m1 & 7;

  size_t bofs[2];   // code-fragment offsets: code = wb + ct*32 + ln
#pragma unroll
  for (int ct = 0; ct < 2; ++ct) bofs[ct] = (size_t)((wb + (ct << 5) + ln) << 3);

  // prefetch chunk 0 code fragments
  bf16x8 pch[2], pcl[2];
#pragma unroll
  for (int ct = 0; ct < 2; ++ct) {
    const short* p = wtil + ((size_t)half << 12) + bofs[ct];
    pch[ct] = *(const bf16x8*)p;
    pcl[ct] = *(const bf16x8*)(p + 131072);
  }

#pragma unroll
  for (int ch = 0; ch < 16; ++ch) {
    const int kg = (ch << 1) + half;
    bf16x8 xh0 = *(const bf16x8*)&xh[a0base + ((kg ^ a0sw) << 3)];
    bf16x8 xl0 = *(const bf16x8*)&xl[a0base + ((kg ^ a0sw) << 3)];
    bf16x8 xh1 = *(const bf16x8*)&xh[a1base + ((kg ^ a1sw) << 3)];
    bf16x8 xl1 = *(const bf16x8*)&xl[a1base + ((kg ^ a1sw) << 3)];
    bf16x8 cfh[2], cfl[2];
#pragma unroll
    for (int ct = 0; ct < 2; ++ct) { cfh[ct] = pch[ct]; cfl[ct] = pcl[ct]; }
    if (ch < 15) {
      const int kgn = ((ch + 1) << 1) + half;
#pragma unroll
      for (int ct = 0; ct < 2; ++ct) {
        const short* p = wtil + ((size_t)kgn << 12) + bofs[ct];
        pch[ct] = *(const bf16x8*)p;
        pcl[ct] = *(const bf16x8*)(p + 131072);
      }
    }
#pragma unroll
    for (int ct = 0; ct < 2; ++ct) {
      acc[ct][0] = __builtin_amdgcn_mfma_f32_32x32x16_bf16(cfh[ct], xh0, acc[ct][0], 0, 0, 0);
      acc[ct][0] = __builtin_amdgcn_mfma_f32_32x32x16_bf16(cfh[ct], xl0, acc[ct][0], 0, 0, 0);
      acc[ct][0] = __builtin_amdgcn_mfma_f32_32x32x16_bf16(cfl[ct], xh0, acc[ct][0], 0, 0, 0);
      acc[ct][1] = __builtin_amdgcn_mfma_f32_32x32x16_bf16(cfh[ct], xh1, acc[ct][1], 0, 0, 0);
      acc[ct][1] = __builtin_amdgcn_mfma_f32_32x32x16_bf16(cfh[ct], xl1, acc[ct][1], 0, 0, 0);
      acc[ct][1] = __builtin_amdgcn_mfma_f32_32x32x16_bf16(cfl[ct], xh1, acc[ct][1], 0, 0, 0);
    }
  }

  // ---- epilogue: per-lane register scan over 32 codes, one xor-32 merge
  float e2r[2][16];
#pragma unroll
  for (int ct = 0; ct < 2; ++ct)
#pragma unroll
    for (int r = 0; r < 16; ++r)
      e2r[ct][r] = e2s[wb + (ct << 5) + (r & 3) + ((r >> 2) << 3) + (half << 2)];

#pragma unroll
  for (int pt = 0; pt < 2; ++pt) {
    float v1 = 3.4e38f, v2 = 3.4e38f;
    int i1 = 0x7fffffff, i2 = 0x7fffffff;
#pragma unroll
    for (int ct = 0; ct < 2; ++ct) {
#pragma unroll
      for (int r = 0; r < 16; ++r) {
        int k = wb + (ct << 5) + (r & 3) + ((r >> 2) << 3) + (half << 2);
        float s = fmaf(-2.f, acc[ct][pt][r], e2r[ct][r]);
        if (lex_lt(s, k, v1, i1)) { v2 = v1; i2 = i1; v1 = s; i1 = k; }
        else if (lex_lt(s, k, v2, i2)) { v2 = s; i2 = k; }
      }
    }
    {
      float ov1 = __shfl_xor(v1, 32);
      int   oi1 = __shfl_xor(i1, 32);
      float ov2 = __shfl_xor(v2, 32);
      int   oi2 = __shfl_xor(i2, 32);
      bool aFirst = lex_lt(v1, i1, ov1, oi1);
      float nv1 = aFirst ? v1 : ov1;  int ni1 = aFirst ? i1 : oi1;
      float cv  = aFirst ? ov1 : v1;  int ci  = aFirst ? oi1 : i1;
      float sv  = aFirst ? v2 : ov2;  int si  = aFirst ? i2 : oi2;
      bool cFirst = lex_lt(cv, ci, sv, si);
      v1 = nv1; i1 = ni1;
      v2 = cFirst ? cv : sv; i2 = cFirst ? ci : si;
    }
    if (half == 0) {
      int s = (wv << 6) + (pt << 5) + ln;
      tv1[s] = v1; ti1[s] = i1; tv2[s] = v2; ti2[s] = i2;
    }
  }
  __syncthreads();

  // ---- final cross-wave merge + fp64 refinement (exact x, w from global)
  if (tid < 64) {
    int row = tid;
    float v1 = 3.4e38f, v2 = 3.4e38f;
    int i1 = 0x7fffffff, i2 = 0x7fffffff;
#pragma unroll
    for (int wvv = 0; wvv < 8; ++wvv) {
      int s = (wvv << 6) + row;
      float a1 = tv1[s]; int ai = ti1[s];
      float a2 = tv2[s]; int bi = ti2[s];
      if (lex_lt(a1, ai, v1, i1)) { v2 = v1; i2 = i1; v1 = a1; i1 = ai; }
      else if (lex_lt(a1, ai, v2, i2)) { v2 = a1; i2 = ai; }
      if (lex_lt(a2, bi, v1, i1)) { v2 = v1; i2 = i1; v1 = a2; i1 = bi; }
      else if (lex_lt(a2, bi, v2, i2)) { v2 = a2; i2 = bi; }
    }
    int pick = i1;
    // window 0.01: >3x the worst-case 3-split+fp32-accum ordering error (~3e-3
    // paranoid bound, ~5e-5 typical); round-7 window 0.05 fired ~4x too often.
    if (v2 - v1 < 0.01f) {
      double s1 = 0.0, s2 = 0.0;
      const float* xp = x + (size_t)b * 262144 + n0 + row;
#pragma unroll 4
      for (int k = 0; k < 256; ++k) {
        double xv = (double)xp[(size_t)k * 1024];
        double w1 = (double)w[k * 512 + i1];
        double w2 = (double)w[k * 512 + i2];
        double t1 = xv - w1, t2 = xv - w2;
        s1 = fma(t1, t1, s1);
        s2 = fma(t2, t2, s2);
      }
      if (s2 < s1 || (s2 == s1 && i2 < i1)) pick = i2;
    }
    int p = b * 1024 + n0 + row;
    arg_out[p] = (float)pick;
    pickS[row] = pick;
  }
  __syncthreads();

  // ---- gather
  if (wT) {
    // scatter-free: coalesced wT row reads -> LDS bounce (stride 33/265 pads
    // keep banks <=2-way) -> coalesced float4 out stores.
    float* gbuf = (float*)arena;   // 64 x 265 floats; xh/xl/e2s/tv1-head are dead
    {
      const int pos  = tid >> 3;
      const int dseg = tid & 7;
      const float* wrow = wT + (size_t)pickS[pos] * 256;
#pragma unroll
      for (int j = 0; j < 8; ++j) {
        float4 v = *(const float4*)(wrow + j * 32 + dseg * 4);
        int base = pos * 265 + j * 33 + dseg * 4;
        gbuf[base]     = v.x;
        gbuf[base + 1] = v.y;
        gbuf[base + 2] = v.z;
        gbuf[base + 3] = v.w;
      }
    }
    __syncthreads();
    {
      const int nn0 = (tid & 15) << 2;
      const int d0g = tid >> 4;          // 0..31
      float* obase = out + (size_t)b * 262144 + n0 + nn0;
#pragma unroll
      for (int dg = 0; dg < 8; ++dg) {
        int d = d0g + (dg << 5);
        int sa = (d >> 5) * 33 + (d & 31);
        float4 o;
        o.x = gbuf[(nn0 + 0) * 265 + sa];
        o.y = gbuf[(nn0 + 1) * 265 + sa];
        o.z = gbuf[(nn0 + 2) * 265 + sa];
        o.w = gbuf[(nn0 + 3) * 265 + sa];
        *(float4*)(obase + (size_t)d * 1024) = o;
      }
    }
  } else {
    // fallback: scattered gather straight from w
    const int nn0 = (tid & 15) << 2;
    const int d0g = tid >> 4;
    int pk0 = pickS[nn0], pk1 = pickS[nn0 + 1], pk2 = pickS[nn0 + 2], pk3 = pickS[nn0 + 3];
    float* obase = out + (size_t)b * 262144 + n0 + nn0;
#pragma unroll
    for (int dg = 0; dg < 8; ++dg) {
      int d = d0g + (dg << 5);
      const float* wr = w + d * 512;
      float4 o = make_float4(wr[pk0], wr[pk1], wr[pk2], wr[pk3]);
      *(float4*)(obase + (size_t)d * 1024) = o;
    }
  }
}

// ---------------------------------------------------------------------------
extern "C" void kernel_launch(void* const* d_in, const int* in_sizes, int n_in,
                              void* d_out, int out_size, void* d_ws, size_t ws_size,
                              hipStream_t stream) {
  const float* x = (const float*)d_in[0];
  const float* w = (const float*)d_in[1];
  float* out  = (float*)d_out;
  float* argf = out + 8388608;
  float* e2   = (float*)d_ws;                       // 512 floats (2048 B)
  short* wtil = (short*)((char*)d_ws + 2048);       // 512 KB
  size_t need = 2048 + 524288 + 524288;
  float* wT   = (ws_size >= need) ? (float*)((char*)d_ws + 2048 + 524288) : nullptr;

  vq_pre<<<72, 256, 0, stream>>>(w, e2, wtil, wT);
  vq_main<<<512, 512, 0, stream>>>(x, w, e2, wtil, wT, out, argf);
}

// Round 10
// 124.100 us; speedup vs baseline: 1.4185x; 1.1048x over previous
//
#include <hip/hip_runtime.h>

typedef __attribute__((ext_vector_type(8))) short bf16x8;
typedef __attribute__((ext_vector_type(16))) float f32x16;

__device__ __forceinline__ bool lex_lt(float av, int ai, float bv, int bi) {
  return av < bv || (av == bv && ai < bi);
}

// round-to-nearest-even fp32 -> bf16 (low 16 bits)
__device__ __forceinline__ unsigned bf16_rne(float v) {
  unsigned u = __float_as_uint(v);
  return (u + 0x7fffu + ((u >> 16) & 1u)) >> 16;
}

// packed RNE bf16 convert of (a,b) -> one 32-bit word (low=a, high=b)
__device__ __forceinline__ unsigned pk_bf16(float a, float b) {
  return bf16_rne(a) | (bf16_rne(b) << 16);
}

// ---------------------------------------------------------------------------
// vq_pre: blocks 0..63 build k-major bf16-split codebook planes
// wh[kg][n][8], wl[kg][n][8] + exact fp32 transposed codebook wT[n][d];
// blocks 64..71: e2[k] in fp64 (4-way d-split per k).
// ---------------------------------------------------------------------------
__global__ __launch_bounds__(256) void vq_pre(
    const float* __restrict__ w, float* __restrict__ e2,
    short* __restrict__ wtil, float* __restrict__ wT) {
  int blk = blockIdx.x;
  if (blk < 64) {
    int gid = blk * 256 + threadIdx.x;  // 16384 threads
    int n  = gid & 511;
    int kg = gid >> 9;
    bf16x8 hv, lv;
    float vv[8];
#pragma unroll
    for (int j = 0; j < 8; ++j) {
      float v = w[(kg * 8 + j) * 512 + n];
      vv[j] = v;
      unsigned h = bf16_rne(v);
      float hf = __uint_as_float(h << 16);
      unsigned l = bf16_rne(v - hf);
      hv[j] = (short)h;
      lv[j] = (short)l;
    }
    short* dst = wtil + (size_t)gid * 8;   // (kg*512 + n)*8
    *(bf16x8*)dst = hv;
    *(bf16x8*)(dst + 131072) = lv;
    if (wT) {
      float* p = wT + (size_t)n * 256 + kg * 8;
      *(float4*)p       = make_float4(vv[0], vv[1], vv[2], vv[3]);
      *(float4*)(p + 4) = make_float4(vv[4], vv[5], vv[6], vv[7]);
    }
  } else {
    int t = (blk - 64) * 256 + threadIdx.x;  // 0..2047
    int k = t >> 2;
    int part = t & 3;
    double s = 0.0;
#pragma unroll 8
    for (int d = part * 64; d < part * 64 + 64; ++d) {
      double v = (double)w[d * 512 + k];
      s = fma(v, v, s);
    }
    s += __shfl_xor(s, 1);
    s += __shfl_xor(s, 2);
    if (part == 0) e2[k] = (float)s;
  }
}

// ---------------------------------------------------------------------------
// vq_main: 256 blocks (exactly 1/CU), 512 threads (8 waves).
// Block = 128 positions x 512 codes. Transposed MFMA (A=codes, B=x):
// wave wv owns codes [wv*64, wv*64+64) over all 128 positions; acc[2][4].
// Parallel fp64 tie refinement (one wave per needy row). LDS-bounce gather.
// ---------------------------------------------------------------------------
__global__ __launch_bounds__(512, 2) void vq_main(
    const float* __restrict__ x, const float* __restrict__ w,
    const float* __restrict__ e2g, const short* __restrict__ wtil,
    const float* __restrict__ wT,
    float* __restrict__ out, float* __restrict__ arg_out) {
  __shared__ __align__(16) char arena[151552];
  short* xh   = (short*)arena;                 // [m][k] swizzled, 64 KB
  short* xl   = (short*)(arena + 65536);       // 64 KB
  float* e2s  = (float*)(arena + 131072);      // 2 KB
  float* tv1  = (float*)(arena + 133120);      // [8][128]
  float* tv2  = (float*)(arena + 137216);
  int*   ti1  = (int*)(arena + 141312);
  int*   ti2  = (int*)(arena + 145408);
  int*   p1S  = (int*)(arena + 149504);        // [128]
  int*   p2S  = (int*)(arena + 150016);
  int*   needS= (int*)(arena + 150528);
  int*   rpickS=(int*)(arena + 151040);
  // gather phase: gbuf = 128 x 265 floats at offset 0 (135680 B; xh/xl/e2s/tv dead)
  float* gbuf = (float*)arena;

  const int tid = threadIdx.x;
  const int b  = blockIdx.x >> 3;
  const int n0 = (blockIdx.x & 7) << 7;        // 128 positions
  const float* xbase = x + (size_t)b * 262144 + n0;

  // ---- staging: per thread 2 reps x (8 coalesced float4 loads -> pack -> 8 b128 writes)
  {
    const int n4  = tid & 31;       // m base / 4 (0..31 -> m 0..124)
    const int kgp = tid >> 5;       // 0..15
#pragma unroll
    for (int rep = 0; rep < 2; ++rep) {
      int kg = kgp + (rep << 4);
      float4 v[8];
#pragma unroll
      for (int j = 0; j < 8; ++j)
        v[j] = *(const float4*)(xbase + (size_t)(kg * 8 + j) * 1024 + (n4 << 2));
#pragma unroll
      for (int i = 0; i < 4; ++i) {
        int m = (n4 << 2) + i;
        union { int w4[4]; bf16x8 v8; } H, L;
#pragma unroll
        for (int jj = 0; jj < 4; ++jj) {
          float a = (i == 0) ? v[2*jj].x : (i == 1) ? v[2*jj].y : (i == 2) ? v[2*jj].z : v[2*jj].w;
          float c = (i == 0) ? v[2*jj+1].x : (i == 1) ? v[2*jj+1].y : (i == 2) ? v[2*jj+1].z : v[2*jj+1].w;
          unsigned hu = pk_bf16(a, c);
          float haf = __uint_as_float(hu << 16);
          float hcf = __uint_as_float(hu & 0xffff0000u);
          unsigned lu = pk_bf16(a - haf, c - hcf);
          H.w4[jj] = (int)hu;
          L.w4[jj] = (int)lu;
        }
        int off = (m << 8) + ((kg ^ (m & 7)) << 3);
        *(bf16x8*)&xh[off] = H.v8;
        *(bf16x8*)&xl[off] = L.v8;
      }
    }
    e2s[tid] = e2g[tid];
  }
  __syncthreads();

  const int lane = tid & 63;
  const int wv   = tid >> 6;     // wave 0..7: codes [wv*64, wv*64+64)
  const int ln   = lane & 31;
  const int half = lane >> 5;
  const int wb   = wv << 6;

  f32x16 acc[2][4];   // [code-tile ct][pos-tile pt]
#pragma unroll
  for (int ct = 0; ct < 2; ++ct)
#pragma unroll
    for (int pt = 0; pt < 4; ++pt)
#pragma unroll
      for (int r = 0; r < 16; ++r) acc[ct][pt][r] = 0.f;

  const int asw = ln & 7;                    // (pt*32+ln)&7 == ln&7
  const int abase = ln << 8;                 // + pt*8192

  int bofs[2];
#pragma unroll
  for (int ct = 0; ct < 2; ++ct) bofs[ct] = (wb + (ct << 5) + ln) << 3;

  bf16x8 pch[2], pcl[2];
#pragma unroll
  for (int ct = 0; ct < 2; ++ct) {
    const short* p = wtil + (half << 12) + bofs[ct];
    pch[ct] = *(const bf16x8*)p;
    pcl[ct] = *(const bf16x8*)(p + 131072);
  }

#pragma unroll
  for (int ch = 0; ch < 16; ++ch) {
    const int kg = (ch << 1) + half;
    const int ao = abase + ((kg ^ asw) << 3);
    bf16x8 xf[4], xg[4];
#pragma unroll
    for (int pt = 0; pt < 4; ++pt) {
      xf[pt] = *(const bf16x8*)&xh[ao + (pt << 13)];
      xg[pt] = *(const bf16x8*)&xl[ao + (pt << 13)];
    }
    bf16x8 cfh[2], cfl[2];
#pragma unroll
    for (int ct = 0; ct < 2; ++ct) { cfh[ct] = pch[ct]; cfl[ct] = pcl[ct]; }
    if (ch < 15) {
      const int kgn = ((ch + 1) << 1) + half;
#pragma unroll
      for (int ct = 0; ct < 2; ++ct) {
        const short* p = wtil + (kgn << 12) + bofs[ct];
        pch[ct] = *(const bf16x8*)p;
        pcl[ct] = *(const bf16x8*)(p + 131072);
      }
    }
#pragma unroll
    for (int ct = 0; ct < 2; ++ct)
#pragma unroll
      for (int pt = 0; pt < 4; ++pt) {
        acc[ct][pt] = __builtin_amdgcn_mfma_f32_32x32x16_bf16(cfh[ct], xf[pt], acc[ct][pt], 0, 0, 0);
        acc[ct][pt] = __builtin_amdgcn_mfma_f32_32x32x16_bf16(cfh[ct], xg[pt], acc[ct][pt], 0, 0, 0);
        acc[ct][pt] = __builtin_amdgcn_mfma_f32_32x32x16_bf16(cfl[ct], xf[pt], acc[ct][pt], 0, 0, 0);
      }
  }

  // ---- epilogue: per-lane register scan (codes in regs), one xor-32 merge
  float e2r[2][16];
#pragma unroll
  for (int ct = 0; ct < 2; ++ct)
#pragma unroll
    for (int r = 0; r < 16; ++r)
      e2r[ct][r] = e2s[wb + (ct << 5) + (r & 3) + ((r >> 2) << 3) + (half << 2)];

#pragma unroll
  for (int pt = 0; pt < 4; ++pt) {
    float v1 = 3.4e38f, v2 = 3.4e38f;
    int i1 = 0x7fffffff, i2 = 0x7fffffff;
#pragma unroll
    for (int ct = 0; ct < 2; ++ct) {
#pragma unroll
      for (int r = 0; r < 16; ++r) {
        int k = wb + (ct << 5) + (r & 3) + ((r >> 2) << 3) + (half << 2);
        float s = fmaf(-2.f, acc[ct][pt][r], e2r[ct][r]);
        if (lex_lt(s, k, v1, i1)) { v2 = v1; i2 = i1; v1 = s; i1 = k; }
        else if (lex_lt(s, k, v2, i2)) { v2 = s; i2 = k; }
      }
    }
    {
      float ov1 = __shfl_xor(v1, 32);
      int   oi1 = __shfl_xor(i1, 32);
      float ov2 = __shfl_xor(v2, 32);
      int   oi2 = __shfl_xor(i2, 32);
      bool aFirst = lex_lt(v1, i1, ov1, oi1);
      float nv1 = aFirst ? v1 : ov1;  int ni1 = aFirst ? i1 : oi1;
      float cv  = aFirst ? ov1 : v1;  int ci  = aFirst ? oi1 : i1;
      float sv  = aFirst ? v2 : ov2;  int si  = aFirst ? i2 : oi2;
      bool cFirst = lex_lt(cv, ci, sv, si);
      v1 = nv1; i1 = ni1;
      v2 = cFirst ? cv : sv; i2 = cFirst ? ci : si;
    }
    if (half == 0) {
      int s = (wv << 7) + (pt << 5) + ln;
      tv1[s] = v1; ti1[s] = i1; tv2[s] = v2; ti2[s] = i2;
    }
  }
  __syncthreads();

  // ---- cross-wave merge (tid<128), publish top-2 + need flag
  if (tid < 128) {
    int row = tid;
    float v1 = 3.4e38f, v2 = 3.4e38f;
    int i1 = 0x7fffffff, i2 = 0x7fffffff;
#pragma unroll
    for (int wvv = 0; wvv < 8; ++wvv) {
      int s = (wvv << 7) + row;
      float a1 = tv1[s]; int ai = ti1[s];
      float a2 = tv2[s]; int bi = ti2[s];
      if (lex_lt(a1, ai, v1, i1)) { v2 = v1; i2 = i1; v1 = a1; i1 = ai; }
      else if (lex_lt(a1, ai, v2, i2)) { v2 = a1; i2 = ai; }
      if (lex_lt(a2, bi, v1, i1)) { v2 = v1; i2 = i1; v1 = a2; i1 = bi; }
      else if (lex_lt(a2, bi, v2, i2)) { v2 = a2; i2 = bi; }
    }
    p1S[row] = i1; p2S[row] = i2;
    needS[row] = (v2 - v1 < 0.01f) ? 1 : 0;   // >3x worst-case split-GEMM jitter
    rpickS[row] = i1;
  }
  __syncthreads();

  // ---- parallel fp64 refinement: wave wv handles rows wv, wv+8, ...
  for (int t = 0; t < 16; ++t) {
    int row = (t << 3) + wv;
    if (needS[row]) {
      int i1 = p1S[row], i2 = p2S[row];
      const float* xp = x + (size_t)b * 262144 + n0 + row;
      double s1 = 0.0, s2 = 0.0;
      int k0 = lane << 2;
#pragma unroll
      for (int i = 0; i < 4; ++i) {
        int k = k0 + i;
        double xv = (double)xp[(size_t)k * 1024];
        double w1 = (double)w[k * 512 + i1];
        double w2 = (double)w[k * 512 + i2];
        double t1 = xv - w1, t2 = xv - w2;
        s1 = fma(t1, t1, s1);
        s2 = fma(t2, t2, s2);
      }
#pragma unroll
      for (int off = 32; off >= 1; off >>= 1) {
        s1 += __shfl_xor(s1, off);
        s2 += __shfl_xor(s2, off);
      }
      if (lane == 0 && (s2 < s1 || (s2 == s1 && i2 < i1))) rpickS[row] = i2;
    }
  }
  __syncthreads();

  // ---- write argmin + gather via LDS bounce
  if (tid < 128) arg_out[b * 1024 + n0 + tid] = (float)rpickS[tid];

  if (wT) {
    {
      const int pos  = tid >> 2;        // 128 positions, 4 threads each
      const int dseg = tid & 3;
      const float* wrow = wT + (size_t)rpickS[pos] * 256;
#pragma unroll
      for (int j = 0; j < 16; ++j) {
        int d = (j << 4) + (dseg << 2);
        float4 v = *(const float4*)(wrow + d);
        int base = pos * 265 + d + (d >> 5);
        gbuf[base]     = v.x;
        gbuf[base + 1] = v.y;
        gbuf[base + 2] = v.z;
        gbuf[base + 3] = v.w;
      }
    }
    __syncthreads();
    {
      const int nn0 = (tid & 31) << 2;
      const int d0g = tid >> 5;          // 0..15
      float* obase = out + (size_t)b * 262144 + n0 + nn0;
#pragma unroll
      for (int dg = 0; dg < 16; ++dg) {
        int d = d0g + (dg << 4);
        int sa = d + (d >> 5);
        float4 o;
        o.x = gbuf[(nn0 + 0) * 265 + sa];
        o.y = gbuf[(nn0 + 1) * 265 + sa];
        o.z = gbuf[(nn0 + 2) * 265 + sa];
        o.w = gbuf[(nn0 + 3) * 265 + sa];
        *(float4*)(obase + (size_t)d * 1024) = o;
      }
    }
  } else {
    const int nn0 = (tid & 31) << 2;
    const int d0g = tid >> 5;
    int pk0 = rpickS[nn0], pk1 = rpickS[nn0 + 1], pk2 = rpickS[nn0 + 2], pk3 = rpickS[nn0 + 3];
    float* obase = out + (size_t)b * 262144 + n0 + nn0;
#pragma unroll
    for (int dg = 0; dg < 16; ++dg) {
      int d = d0g + (dg << 4);
      const float* wr = w + d * 512;
      float4 o = make_float4(wr[pk0], wr[pk1], wr[pk2], wr[pk3]);
      *(float4*)(obase + (size_t)d * 1024) = o;
    }
  }
}

// ---------------------------------------------------------------------------
extern "C" void kernel_launch(void* const* d_in, const int* in_sizes, int n_in,
                              void* d_out, int out_size, void* d_ws, size_t ws_size,
                              hipStream_t stream) {
  const float* x = (const float*)d_in[0];
  const float* w = (const float*)d_in[1];
  float* out  = (float*)d_out;
  float* argf = out + 8388608;
  float* e2   = (float*)d_ws;                       // 2048 B
  short* wtil = (short*)((char*)d_ws + 2048);       // 512 KB
  size_t need = 2048 + 524288 + 524288;
  float* wT   = (ws_size >= need) ? (float*)((char*)d_ws + 2048 + 524288) : nullptr;

  vq_pre<<<72, 256, 0, stream>>>(w, e2, wtil, wT);
  vq_main<<<256, 512, 0, stream>>>(x, w, e2, wtil, wT, out, argf);
}

// Round 11
// 120.095 us; speedup vs baseline: 1.4658x; 1.0333x over previous
//
#include <hip/hip_runtime.h>

typedef __attribute__((ext_vector_type(8))) short bf16x8;
typedef __attribute__((ext_vector_type(16))) float f32x16;

__device__ __forceinline__ bool lex_lt(float av, int ai, float bv, int bi) {
  return av < bv || (av == bv && ai < bi);
}

// round-to-nearest-even fp32 -> bf16 (low 16 bits)
__device__ __forceinline__ unsigned bf16_rne(float v) {
  unsigned u = __float_as_uint(v);
  return (u + 0x7fffu + ((u >> 16) & 1u)) >> 16;
}

// packed RNE bf16 convert of (a,b) -> one 32-bit word (low=a, high=b)
__device__ __forceinline__ unsigned pk_bf16(float a, float b) {
  return bf16_rne(a) | (bf16_rne(b) << 16);
}

// ---------------------------------------------------------------------------
// vq_pre: blocks 0..63 build k-major bf16-split codebook planes
// wh[kg][n][8], wl[kg][n][8] + exact fp32 transposed codebook wT[n][d];
// blocks 64..71: e2[k] in fp64 (4-way d-split per k).
// ---------------------------------------------------------------------------
__global__ __launch_bounds__(256) void vq_pre(
    const float* __restrict__ w, float* __restrict__ e2,
    short* __restrict__ wtil, float* __restrict__ wT) {
  int blk = blockIdx.x;
  if (blk < 64) {
    int gid = blk * 256 + threadIdx.x;  // 16384 threads
    int n  = gid & 511;
    int kg = gid >> 9;
    bf16x8 hv, lv;
    float vv[8];
#pragma unroll
    for (int j = 0; j < 8; ++j) {
      float v = w[(kg * 8 + j) * 512 + n];
      vv[j] = v;
      unsigned h = bf16_rne(v);
      float hf = __uint_as_float(h << 16);
      unsigned l = bf16_rne(v - hf);
      hv[j] = (short)h;
      lv[j] = (short)l;
    }
    short* dst = wtil + (size_t)gid * 8;   // (kg*512 + n)*8
    *(bf16x8*)dst = hv;
    *(bf16x8*)(dst + 131072) = lv;
    if (wT) {
      float* p = wT + (size_t)n * 256 + kg * 8;
      *(float4*)p       = make_float4(vv[0], vv[1], vv[2], vv[3]);
      *(float4*)(p + 4) = make_float4(vv[4], vv[5], vv[6], vv[7]);
    }
  } else {
    int t = (blk - 64) * 256 + threadIdx.x;  // 0..2047
    int k = t >> 2;
    int part = t & 3;
    double s = 0.0;
#pragma unroll 8
    for (int d = part * 64; d < part * 64 + 64; ++d) {
      double v = (double)w[d * 512 + k];
      s = fma(v, v, s);
    }
    s += __shfl_xor(s, 1);
    s += __shfl_xor(s, 2);
    if (part == 0) e2[k] = (float)s;
  }
}

// ---------------------------------------------------------------------------
// vq_main: 256 blocks (1/CU), 512 threads (8 waves).
// Block = 128 positions x 512 codes. Transposed MFMA (A=codes, B=x).
// Pipelined staging: K-half-1 of x is loaded during K-chunks 0..3 and
// converted/written between chunks 3..4 (region unread until mid-barrier).
// Transposed LDS gather bounce: b128 conflict-free reads.
// ---------------------------------------------------------------------------
__global__ __launch_bounds__(512, 2) void vq_main(
    const float* __restrict__ x, const float* __restrict__ w,
    const float* __restrict__ e2g, const short* __restrict__ wtil,
    const float* __restrict__ wT,
    float* __restrict__ out, float* __restrict__ arg_out) {
  __shared__ __align__(16) char arena[151552];
  short* xh   = (short*)arena;                 // [m][k] swizzled, 64 KB
  short* xl   = (short*)(arena + 65536);       // 64 KB
  float* e2s  = (float*)(arena + 131072);      // 2 KB
  float* tv1  = (float*)(arena + 133120);      // [8][128]
  float* tv2  = (float*)(arena + 137216);
  int*   ti1  = (int*)(arena + 141312);
  int*   ti2  = (int*)(arena + 145408);
  int*   p1S  = (int*)(arena + 149504);        // [128]
  int*   p2S  = (int*)(arena + 150016);
  int*   needS= (int*)(arena + 150528);
  int*   rpickS=(int*)(arena + 151040);
  // gather phase: gbuf[d*132 + pos], 256x132 floats = 135168 B (xh/xl/e2s/tv dead)
  float* gbuf = (float*)arena;

  const int tid = threadIdx.x;
  const int b  = blockIdx.x >> 3;
  const int n0 = (blockIdx.x & 7) << 7;        // 128 positions
  const float* xbase = x + (size_t)b * 262144 + n0;

  const int n4  = tid & 31;       // m base / 4 (0..31)
  const int kgp = tid >> 5;       // 0..15

  auto load8 = [&](int kg, float4* v) {
#pragma unroll
    for (int j = 0; j < 8; ++j)
      v[j] = *(const float4*)(xbase + (size_t)(kg * 8 + j) * 1024 + (n4 << 2));
  };
  auto convert_write = [&](int kg, const float4* v) {
#pragma unroll
    for (int i = 0; i < 4; ++i) {
      int m = (n4 << 2) + i;
      union { int w4[4]; bf16x8 v8; } H, L;
#pragma unroll
      for (int jj = 0; jj < 4; ++jj) {
        float a = (i == 0) ? v[2*jj].x : (i == 1) ? v[2*jj].y : (i == 2) ? v[2*jj].z : v[2*jj].w;
        float c = (i == 0) ? v[2*jj+1].x : (i == 1) ? v[2*jj+1].y : (i == 2) ? v[2*jj+1].z : v[2*jj+1].w;
        unsigned hu = pk_bf16(a, c);
        float haf = __uint_as_float(hu << 16);
        float hcf = __uint_as_float(hu & 0xffff0000u);
        unsigned lu = pk_bf16(a - haf, c - hcf);
        H.w4[jj] = (int)hu;
        L.w4[jj] = (int)lu;
      }
      int off = (m << 8) + ((kg ^ (m & 7)) << 3);
      *(bf16x8*)&xh[off] = H.v8;
      *(bf16x8*)&xl[off] = L.v8;
    }
  };

  // ---- stage K-half-0 (kg 0..15)
  {
    float4 v0[8];
    load8(kgp, v0);
    convert_write(kgp, v0);
    e2s[tid] = e2g[tid];
  }
  __syncthreads();

  const int lane = tid & 63;
  const int wv   = tid >> 6;     // wave 0..7: codes [wv*64, wv*64+64)
  const int ln   = lane & 31;
  const int half = lane >> 5;
  const int wb   = wv << 6;

  f32x16 acc[2][4];   // [code-tile ct][pos-tile pt]
#pragma unroll
  for (int ct = 0; ct < 2; ++ct)
#pragma unroll
    for (int pt = 0; pt < 4; ++pt)
#pragma unroll
      for (int r = 0; r < 16; ++r) acc[ct][pt][r] = 0.f;

  const int asw = ln & 7;
  const int abase = ln << 8;

  int bofs[2];
#pragma unroll
  for (int ct = 0; ct < 2; ++ct) bofs[ct] = (wb + (ct << 5) + ln) << 3;

  bf16x8 pch[2], pcl[2];
#pragma unroll
  for (int ct = 0; ct < 2; ++ct) {
    const short* p = wtil + (half << 12) + bofs[ct];
    pch[ct] = *(const bf16x8*)p;
    pcl[ct] = *(const bf16x8*)(p + 131072);
  }

  auto kstep = [&](int ch) {
    const int kg = (ch << 1) + half;
    const int ao = abase + ((kg ^ asw) << 3);
    bf16x8 xf[4], xg[4];
#pragma unroll
    for (int pt = 0; pt < 4; ++pt) {
      xf[pt] = *(const bf16x8*)&xh[ao + (pt << 13)];
      xg[pt] = *(const bf16x8*)&xl[ao + (pt << 13)];
    }
    bf16x8 cfh[2], cfl[2];
#pragma unroll
    for (int ct = 0; ct < 2; ++ct) { cfh[ct] = pch[ct]; cfl[ct] = pcl[ct]; }
    if (ch < 15) {
      const int kgn = ((ch + 1) << 1) + half;
#pragma unroll
      for (int ct = 0; ct < 2; ++ct) {
        const short* p = wtil + (kgn << 12) + bofs[ct];
        pch[ct] = *(const bf16x8*)p;
        pcl[ct] = *(const bf16x8*)(p + 131072);
      }
    }
#pragma unroll
    for (int ct = 0; ct < 2; ++ct)
#pragma unroll
      for (int pt = 0; pt < 4; ++pt) {
        acc[ct][pt] = __builtin_amdgcn_mfma_f32_32x32x16_bf16(cfh[ct], xf[pt], acc[ct][pt], 0, 0, 0);
        acc[ct][pt] = __builtin_amdgcn_mfma_f32_32x32x16_bf16(cfh[ct], xg[pt], acc[ct][pt], 0, 0, 0);
        acc[ct][pt] = __builtin_amdgcn_mfma_f32_32x32x16_bf16(cfl[ct], xf[pt], acc[ct][pt], 0, 0, 0);
      }
  };

  // ---- pipelined: issue K-half-1 x loads, compute chunks 0..3, convert,
  //      compute 4..7, barrier, compute 8..15.
  float4 vx[8];
  load8(kgp + 16, vx);
  kstep(0); kstep(1); kstep(2); kstep(3);
  convert_write(kgp + 16, vx);
  kstep(4); kstep(5); kstep(6); kstep(7);
  __syncthreads();
  kstep(8); kstep(9); kstep(10); kstep(11);
  kstep(12); kstep(13); kstep(14); kstep(15);

  // ---- epilogue: per-lane register scan (codes in regs), one xor-32 merge
  float e2r[2][16];
#pragma unroll
  for (int ct = 0; ct < 2; ++ct)
#pragma unroll
    for (int r = 0; r < 16; ++r)
      e2r[ct][r] = e2s[wb + (ct << 5) + (r & 3) + ((r >> 2) << 3) + (half << 2)];

#pragma unroll
  for (int pt = 0; pt < 4; ++pt) {
    float v1 = 3.4e38f, v2 = 3.4e38f;
    int i1 = 0x7fffffff, i2 = 0x7fffffff;
#pragma unroll
    for (int ct = 0; ct < 2; ++ct) {
#pragma unroll
      for (int r = 0; r < 16; ++r) {
        int k = wb + (ct << 5) + (r & 3) + ((r >> 2) << 3) + (half << 2);
        float s = fmaf(-2.f, acc[ct][pt][r], e2r[ct][r]);
        if (lex_lt(s, k, v1, i1)) { v2 = v1; i2 = i1; v1 = s; i1 = k; }
        else if (lex_lt(s, k, v2, i2)) { v2 = s; i2 = k; }
      }
    }
    {
      float ov1 = __shfl_xor(v1, 32);
      int   oi1 = __shfl_xor(i1, 32);
      float ov2 = __shfl_xor(v2, 32);
      int   oi2 = __shfl_xor(i2, 32);
      bool aFirst = lex_lt(v1, i1, ov1, oi1);
      float nv1 = aFirst ? v1 : ov1;  int ni1 = aFirst ? i1 : oi1;
      float cv  = aFirst ? ov1 : v1;  int ci  = aFirst ? oi1 : i1;
      float sv  = aFirst ? v2 : ov2;  int si  = aFirst ? i2 : oi2;
      bool cFirst = lex_lt(cv, ci, sv, si);
      v1 = nv1; i1 = ni1;
      v2 = cFirst ? cv : sv; i2 = cFirst ? ci : si;
    }
    if (half == 0) {
      int s = (wv << 7) + (pt << 5) + ln;
      tv1[s] = v1; ti1[s] = i1; tv2[s] = v2; ti2[s] = i2;
    }
  }
  __syncthreads();

  // ---- cross-wave merge (tid<128), publish top-2 + need flag
  if (tid < 128) {
    int row = tid;
    float v1 = 3.4e38f, v2 = 3.4e38f;
    int i1 = 0x7fffffff, i2 = 0x7fffffff;
#pragma unroll
    for (int wvv = 0; wvv < 8; ++wvv) {
      int s = (wvv << 7) + row;
      float a1 = tv1[s]; int ai = ti1[s];
      float a2 = tv2[s]; int bi = ti2[s];
      if (lex_lt(a1, ai, v1, i1)) { v2 = v1; i2 = i1; v1 = a1; i1 = ai; }
      else if (lex_lt(a1, ai, v2, i2)) { v2 = a1; i2 = ai; }
      if (lex_lt(a2, bi, v1, i1)) { v2 = v1; i2 = i1; v1 = a2; i1 = bi; }
      else if (lex_lt(a2, bi, v2, i2)) { v2 = a2; i2 = bi; }
    }
    p1S[row] = i1; p2S[row] = i2;
    needS[row] = (v2 - v1 < 0.01f) ? 1 : 0;   // >3x worst-case split-GEMM jitter
    rpickS[row] = i1;
  }
  __syncthreads();

  // ---- parallel fp64 refinement: wave wv handles rows wv, wv+8, ...
  for (int t = 0; t < 16; ++t) {
    int row = (t << 3) + wv;
    if (needS[row]) {
      int i1 = p1S[row], i2 = p2S[row];
      const float* xp = x + (size_t)b * 262144 + n0 + row;
      double s1 = 0.0, s2 = 0.0;
      int k0 = lane << 2;
#pragma unroll
      for (int i = 0; i < 4; ++i) {
        int k = k0 + i;
        double xv = (double)xp[(size_t)k * 1024];
        double w1 = (double)w[k * 512 + i1];
        double w2 = (double)w[k * 512 + i2];
        double t1 = xv - w1, t2 = xv - w2;
        s1 = fma(t1, t1, s1);
        s2 = fma(t2, t2, s2);
      }
#pragma unroll
      for (int off = 32; off >= 1; off >>= 1) {
        s1 += __shfl_xor(s1, off);
        s2 += __shfl_xor(s2, off);
      }
      if (lane == 0 && (s2 < s1 || (s2 == s1 && i2 < i1))) rpickS[row] = i2;
    }
  }
  __syncthreads();

  // ---- write argmin + gather via transposed LDS bounce
  if (tid < 128) arg_out[b * 1024 + n0 + tid] = (float)rpickS[tid];

  if (wT) {
    {
      const int pos  = tid >> 2;        // 128 positions, 4 threads each
      const int dseg = tid & 3;
      const float* wrow = wT + (size_t)rpickS[pos] * 256;
#pragma unroll
      for (int j = 0; j < 16; ++j) {
        int d0 = (j << 4) + (dseg << 2);
        float4 v = *(const float4*)(wrow + d0);
        gbuf[(d0 + 0) * 132 + pos] = v.x;
        gbuf[(d0 + 1) * 132 + pos] = v.y;
        gbuf[(d0 + 2) * 132 + pos] = v.z;
        gbuf[(d0 + 3) * 132 + pos] = v.w;
      }
    }
    __syncthreads();
    {
      const int nn0 = (tid & 31) << 2;
      const int d0g = tid >> 5;          // 0..15
      float* obase = out + (size_t)b * 262144 + n0 + nn0;
#pragma unroll
      for (int dg = 0; dg < 16; ++dg) {
        int d = d0g + (dg << 4);
        float4 o = *(const float4*)&gbuf[d * 132 + nn0];
        *(float4*)(obase + (size_t)d * 1024) = o;
      }
    }
  } else {
    const int nn0 = (tid & 31) << 2;
    const int d0g = tid >> 5;
    int pk0 = rpickS[nn0], pk1 = rpickS[nn0 + 1], pk2 = rpickS[nn0 + 2], pk3 = rpickS[nn0 + 3];
    float* obase = out + (size_t)b * 262144 + n0 + nn0;
#pragma unroll
    for (int dg = 0; dg < 16; ++dg) {
      int d = d0g + (dg << 4);
      const float* wr = w + d * 512;
      float4 o = make_float4(wr[pk0], wr[pk1], wr[pk2], wr[pk3]);
      *(float4*)(obase + (size_t)d * 1024) = o;
    }
  }
}

// ---------------------------------------------------------------------------
extern "C" void kernel_launch(void* const* d_in, const int* in_sizes, int n_in,
                              void* d_out, int out_size, void* d_ws, size_t ws_size,
                              hipStream_t stream) {
  const float* x = (const float*)d_in[0];
  const float* w = (const float*)d_in[1];
  float* out  = (float*)d_out;
  float* argf = out + 8388608;
  float* e2   = (float*)d_ws;                       // 2048 B
  short* wtil = (short*)((char*)d_ws + 2048);       // 512 KB
  size_t need = 2048 + 524288 + 524288;
  float* wT   = (ws_size >= need) ? (float*)((char*)d_ws + 2048 + 524288) : nullptr;

  vq_pre<<<72, 256, 0, stream>>>(w, e2, wtil, wT);
  vq_main<<<256, 512, 0, stream>>>(x, w, e2, wtil, wT, out, argf);
}